// Round 3
// baseline (259.226 us; speedup 1.0000x reference)
//
#include <hip/hip_runtime.h>
#include <hip/hip_bf16.h>
#include <math.h>

#define N_TOK 65536
#define DIM   256
#define NEXP  8

using frag_ab = __attribute__((ext_vector_type(8))) short;   // 8 bf16 (4 VGPRs)
using frag_cd = __attribute__((ext_vector_type(4))) float;   // 4 fp32 acc

__device__ __forceinline__ unsigned short f2bf(float f) {
  unsigned u = __float_as_uint(f);
  u += 0x7FFFu + ((u >> 16) & 1u);   // RNE
  return (unsigned short)(u >> 16);
}

// async 16B global->LDS: lds base is wave-uniform; lane i lands at base+i*16
__device__ __forceinline__ void gl2lds16(const unsigned short* g, unsigned short* l) {
  __builtin_amdgcn_global_load_lds(
      (const __attribute__((address_space(1))) void*)g,
      (__attribute__((address_space(3))) void*)l, 16, 0, 0);
}

// meta int layout in ws: [0:8)=counts1 [8:16)=counts2 [16:24)=base1
// [24:32)=base2 [32:40)=cursor1 [40:48)=cursor2

// ---- k_prep: Wb = bf16(W) [e][o][d]; c[e][o]=bias_e . W_e[o]; zero meta -----
__global__ __launch_bounds__(256) void k_prep(
    const float* __restrict__ w,      // expert_weight [E][OUT][D]
    const float* __restrict__ bias,   // expert_bias   [E][D]
    unsigned short* __restrict__ Wb,
    float* __restrict__ c,            // [E][OUT]
    int* __restrict__ meta) {
  int b = blockIdx.x, tid = threadIdx.x;
  if (b < 512) {
    int gid = b * 256 + tid;                  // 512*256*4 = 524288 floats
    float4 v = ((const float4*)w)[gid];
    ushort4 h; h.x = f2bf(v.x); h.y = f2bf(v.y); h.z = f2bf(v.z); h.w = f2bf(v.w);
    ((ushort4*)Wb)[gid] = h;
    if (b == 0 && tid < 48) meta[tid] = 0;
  } else {
    int wid = ((b - 512) * 256 + tid) >> 6;   // 0..2047 : one wave per (e,o)
    int lane = tid & 63;
    int e = wid >> 8, o = wid & 255;
    const float* br = bias + e * DIM + lane * 4;
    const float* wr = w + (size_t)(e * 256 + o) * DIM + lane * 4;
    float s = br[0] * wr[0] + br[1] * wr[1] + br[2] * wr[2] + br[3] * wr[3];
    #pragma unroll
    for (int m = 1; m < 64; m <<= 1) s += __shfl_xor(s, m, 64);
    if (lane == 0) c[e * 256 + o] = s;
  }
}

// ---- k_gating: 128 tok/block, 2 threads per token (dim split), f64 ranking --
__global__ __launch_bounds__(256) void k_gating(
    const float* __restrict__ x,      // [N][D]
    const float* __restrict__ wg,     // [D][E]
    unsigned short* __restrict__ xb,  // [N][D] bf16
    int* __restrict__ routeE,         // [N] packed e1 | e2<<8
    float* __restrict__ routeG,       // [N][2]
    int* __restrict__ meta) {
  __shared__ double swg[DIM * NEXP];    // 16 KB
  __shared__ float  chunk[128 * 33];    // 16.9 KB (pad 33 -> conflict-free)
  __shared__ double sPar[128 * NEXP];   // 8 KB
  __shared__ int    hcnt[2 * NEXP];
  int tid = threadIdx.x;
  int tok0 = blockIdx.x * 128;
  int sub = tid >> 7, tk = tid & 127;

  for (int i = tid; i < DIM * NEXP; i += 256) swg[i] = (double)wg[i];
  if (tid < 2 * NEXP) hcnt[tid] = 0;

  double p[NEXP];
  #pragma unroll
  for (int e = 0; e < NEXP; e++) p[e] = 0.0;

  for (int dc = 0; dc < 8; dc++) {      // 8 chunks of 32 dims
    __syncthreads();
    #pragma unroll
    for (int i = 0; i < 4; i++) {       // stage [128 tok][32 dim], coalesced
      int f = i * 256 + tid;
      int r = f >> 3, c4 = (f & 7) * 4;
      const float4 v = *(const float4*)(x + (size_t)(tok0 + r) * DIM + dc * 32 + c4);
      ushort4 h; h.x = f2bf(v.x); h.y = f2bf(v.y); h.z = f2bf(v.z); h.w = f2bf(v.w);
      *(ushort4*)(xb + (size_t)(tok0 + r) * DIM + dc * 32 + c4) = h;
      float* dst = &chunk[r * 33 + c4];
      dst[0] = v.x; dst[1] = v.y; dst[2] = v.z; dst[3] = v.w;
    }
    __syncthreads();
    if ((dc >> 2) == sub) {             // this thread's half of the dims
      #pragma unroll 8
      for (int cc = 0; cc < 32; cc++) {
        double xv = (double)chunk[tk * 33 + cc];
        const double* wrow = &swg[(dc * 32 + cc) * NEXP];  // broadcast read
        #pragma unroll
        for (int e = 0; e < NEXP; e++) p[e] += xv * wrow[e];
      }
    }
  }

  if (sub == 1) {
    #pragma unroll
    for (int e = 0; e < NEXP; e++) sPar[tk * NEXP + e] = p[e];
  }
  __syncthreads();
  if (sub == 0) {
    #pragma unroll
    for (int e = 0; e < NEXP; e++) p[e] += sPar[tk * NEXP + e];

    // top-2 (ties -> lowest index, matches jax.lax.top_k)
    int i1 = 0; double v1 = p[0];
    #pragma unroll
    for (int e = 1; e < NEXP; e++) { if (p[e] > v1) { v1 = p[e]; i1 = e; } }
    int i2 = -1; double v2 = -1e300;
    #pragma unroll
    for (int e = 0; e < NEXP; e++) { if (e != i1 && p[e] > v2) { v2 = p[e]; i2 = e; } }
    double t = exp(v2 - v1);
    float g1 = (float)(1.0 / (1.0 + t));
    float g2 = 1.0f - g1;

    int n = tok0 + tk;
    routeE[n] = i1 | (i2 << 8);
    *(float2*)(routeG + 2 * (size_t)n) = make_float2(g1, g2);
    atomicAdd(&hcnt[i1], 1);
    atomicAdd(&hcnt[NEXP + i2], 1);
  }
  __syncthreads();
  if (tid < 2 * NEXP) atomicAdd(&meta[tid], hcnt[tid]);
}

// ---- k_scan: 128-aligned exclusive scans -> base1/2, cursor1/2 --------------
__global__ void k_scan(int* __restrict__ meta) {
  if (threadIdx.x == 0) {
    int run = 0;
    for (int e = 0; e < NEXP; e++) {
      meta[16 + e] = run; meta[32 + e] = run;          // base1, cursor1
      run += ((meta[e] + 127) >> 7) << 7;
    }
    run = 0;
    for (int e = 0; e < NEXP; e++) {
      meta[24 + e] = run; meta[40 + e] = run;          // base2, cursor2
      run += ((meta[8 + e] + 127) >> 7) << 7;
    }
  }
}

// ---- k_scatter: two expert-grouped permutations (first/second choice) -------
__global__ __launch_bounds__(1024) void k_scatter(
    const int* __restrict__ routeE, const float* __restrict__ routeG,
    int* __restrict__ meta,
    int* __restrict__ srcTok1, float* __restrict__ srcGate1,
    int* __restrict__ srcTok2, float* __restrict__ srcGate2) {
  __shared__ int cnt[2 * NEXP], bse[2 * NEXP];
  int tid = threadIdx.x;
  if (tid < 2 * NEXP) cnt[tid] = 0;
  __syncthreads();
  int n = blockIdx.x * 1024 + tid;
  int ep = routeE[n];
  int e1 = ep & 255, e2 = ep >> 8;
  float2 g = *(const float2*)(routeG + 2 * (size_t)n);
  int r1 = atomicAdd(&cnt[e1], 1);
  int r2 = atomicAdd(&cnt[NEXP + e2], 1);
  __syncthreads();
  if (tid < NEXP)            bse[tid] = atomicAdd(&meta[32 + tid], cnt[tid]);
  else if (tid < 2 * NEXP)   bse[tid] = atomicAdd(&meta[40 + (tid - NEXP)], cnt[tid]);
  __syncthreads();
  int p1 = bse[e1] + r1;
  srcTok1[p1] = n; srcGate1[p1] = g.x;
  int p2 = bse[NEXP + e2] + r2;
  srcTok2[p2] = n; srcGate2[p2] = g.y;
}

// ---- k_gemm: grouped GEMM. BM=128, BN=256 (full OUT), BK=64, 512 thr/8 waves
// A fetched ONCE per pass (no nt split). Proven minimum 2-phase pipeline
// (catalog T3 recipe): STAGE(next tile) issued BEFORE compute(cur), one
// __syncthreads() per tile (its vmcnt(0)+barrier semantics are exactly the
// drain the pipeline needs -> no inline asm, compiler-managed waits only).
// Source-side XOR swizzle: chunk c of row r lives at LDS pos (c+r)&7
// (8 x 16B chunks per 64-col row) -> conflict-free ds_read_b128.
// mode 0: out[n] = g*(acc - c[e]); mode 1: out[n] += g*(acc - c[e])
__global__ __launch_bounds__(512, 2) void k_gemm(
    const unsigned short* __restrict__ xb,
    const unsigned short* __restrict__ Wb,   // [e][o][d]
    const int* __restrict__ counts, const int* __restrict__ base,
    const int* __restrict__ srcTok, const float* __restrict__ srcGate,
    const float* __restrict__ c,
    float* __restrict__ out, int mode) {
  __shared__ unsigned short sA[2][128 * 64];   // 32 KB (2 bufs)
  __shared__ unsigned short sB[2][256 * 64];   // 64 KB (2 bufs)
  __shared__ int   sTok[128];
  __shared__ float sG[128];
  __shared__ float sCor[256];
  int tid = threadIdx.x;

  // map block -> (expert, m-tile)
  int rem = blockIdx.x, e = 0, ne = 0;
  for (e = 0; e < NEXP; e++) {
    ne = counts[e];
    int tiles = (ne + 127) >> 7;
    if (rem < tiles) break;
    rem -= tiles;
  }
  if (e == NEXP) return;
  int mt = rem;
  int slot0 = base[e] + mt * 128;

  if (tid < 128) {
    int idx = mt * 128 + tid;
    bool v = idx < ne;
    sTok[tid] = v ? srcTok[slot0 + tid] : 0;
    sG[tid]   = v ? srcGate[slot0 + tid] : 0.f;
  } else if (tid < 192) {
    ((float4*)sCor)[tid - 128] = ((const float4*)(c + e * 256))[tid - 128];
  }
  __syncthreads();

  int w = tid >> 6, lane = tid & 63;
  int lrow = lane >> 3, lchk = lane & 7;

  // staging: wave w -> A rows [w*16, w*16+16) (2 groups of 8 rows),
  //                    B rows [w*32, w*32+32) (4 groups of 8 rows)
  const unsigned short* aSrc[2];
  const unsigned short* bSrc[4];
  int aOff[2], bOff[4];
  #pragma unroll
  for (int q = 0; q < 2; q++) {
    int r0 = w * 16 + q * 8;
    int r  = r0 + lrow;
    int cc = (lchk - r) & 7;                 // global chunk for this lane's pos
    aSrc[q] = xb + (size_t)sTok[r] * 256 + cc * 8;
    aOff[q] = r0 * 64;                       // wave-uniform LDS base (elements)
  }
  #pragma unroll
  for (int q = 0; q < 4; q++) {
    int r0 = w * 32 + q * 8;
    int r  = r0 + lrow;
    int cc = (lchk - r) & 7;
    bSrc[q] = Wb + (size_t)e * 65536 + (size_t)r * 256 + cc * 8;
    bOff[q] = r0 * 64;
  }

  // fragment read offsets: row ra, k-chunk kc=ks*4+lk -> pos (kc+ra)&7
  int wm = w & 1, wn = w >> 1;               // 2 (m) x 4 (n) waves
  int lr = lane & 15, lk = lane >> 4;
  int offA[2][4], offB[2][4];
  #pragma unroll
  for (int ks = 0; ks < 2; ks++)
    #pragma unroll
    for (int i = 0; i < 4; i++) {
      int ra = wm * 64 + i * 16 + lr;
      offA[ks][i] = ra * 64 + ((ks * 4 + lk + ra) & 7) * 8;
      int rb = wn * 64 + i * 16 + lr;
      offB[ks][i] = rb * 64 + ((ks * 4 + lk + rb) & 7) * 8;
    }

  frag_cd acc[4][4];
  #pragma unroll
  for (int i = 0; i < 4; i++)
    #pragma unroll
    for (int j = 0; j < 4; j++)
      acc[i][j] = (frag_cd){0.f, 0.f, 0.f, 0.f};

#define STAGE(T, BUF) do {                                                  \
    _Pragma("unroll")                                                       \
    for (int q = 0; q < 2; q++) gl2lds16(aSrc[q] + (T) * 64, &sA[BUF][aOff[q]]); \
    _Pragma("unroll")                                                       \
    for (int q = 0; q < 4; q++) gl2lds16(bSrc[q] + (T) * 64, &sB[BUF][bOff[q]]); \
  } while (0)

#define COMPUTE(BUF) do {                                                   \
    const unsigned short* A_ = sA[BUF];                                     \
    const unsigned short* B_ = sB[BUF];                                     \
    _Pragma("unroll")                                                       \
    for (int ks = 0; ks < 2; ks++) {                                        \
      frag_ab av[4], bv[4];                                                 \
      _Pragma("unroll")                                                     \
      for (int i = 0; i < 4; i++) av[i] = *(const frag_ab*)(A_ + offA[ks][i]); \
      _Pragma("unroll")                                                     \
      for (int j = 0; j < 4; j++) bv[j] = *(const frag_ab*)(B_ + offB[ks][j]); \
      _Pragma("unroll")                                                     \
      for (int i = 0; i < 4; i++)                                           \
        _Pragma("unroll")                                                   \
        for (int j = 0; j < 4; j++)                                         \
          acc[i][j] = __builtin_amdgcn_mfma_f32_16x16x32_bf16(av[i], bv[j], acc[i][j], 0, 0, 0); \
    }                                                                       \
  } while (0)

  // K = 256, 4 tiles of BK=64. 2-phase: stage(t+1) issued before compute(t);
  // __syncthreads() = s_waitcnt vmcnt(0) lgkmcnt(0) + s_barrier drains the
  // prefetch and protects buffer reuse (proven structure).
  STAGE(0, 0);
  __syncthreads();               // tile 0 resident
  STAGE(1, 1);                   // prefetch t1 (in flight during compute t0)
  COMPUTE(0);
  __syncthreads();               // t1 resident; buf0 readers done
  STAGE(2, 0);
  COMPUTE(1);
  __syncthreads();               // t2 resident; buf1 readers done
  STAGE(3, 1);
  COMPUTE(0);
  __syncthreads();               // t3 resident; buf0 readers done
  COMPUTE(1);

#undef STAGE
#undef COMPUTE

  // epilogue: C/D layout col=lane&15, row=(lane>>4)*4+reg  [m89-verified]
  #pragma unroll
  for (int i = 0; i < 4; i++) {
    #pragma unroll
    for (int rr = 0; rr < 4; rr++) {
      int m = wm * 64 + i * 16 + lk * 4 + rr;
      if (mt * 128 + m < ne) {             // pad rows: no store
        int tokn = sTok[m];
        float g = sG[m];
        float* orow = out + (size_t)tokn * 256;
        #pragma unroll
        for (int j = 0; j < 4; j++) {
          int col = wn * 64 + j * 16 + lr;
          float v = g * (acc[i][j][rr] - sCor[col]);
          if (mode) v += orow[col];
          orow[col] = v;
        }
      }
    }
  }
}

extern "C" void kernel_launch(void* const* d_in, const int* in_sizes, int n_in,
                              void* d_out, int out_size, void* d_ws, size_t ws_size,
                              hipStream_t stream) {
  const float* x    = (const float*)d_in[0];  // [N][D]
  const float* wg   = (const float*)d_in[1];  // [D][E]
  const float* bias = (const float*)d_in[2];  // [E][D]
  const float* w    = (const float*)d_in[3];  // [E][OUT][D]
  float* out = (float*)d_out;
  char* ws = (char*)d_ws;

  // total ws usage: ~36.5 MB (round-1 proved >=39.6 MB available)
  unsigned short* xb = (unsigned short*)(ws);                 // 33,554,432 B
  unsigned short* Wb = (unsigned short*)(ws + 33554432);      //  1,048,576 B
  float* c           = (float*)(ws + 34603008);               //      8,192 B
  int* meta          = (int*)(ws + 34611200);                 //        256 B
  int* routeE        = (int*)(ws + 34611456);                 //    262,144 B
  float* routeG      = (float*)(ws + 34873600);               //    524,288 B
  int* srcTok1       = (int*)(ws + 35397888);                 //    266,240 B (66560 slots)
  float* srcGate1    = (float*)(ws + 35664128);               //    266,240 B
  int* srcTok2       = (int*)(ws + 35930368);                 //    266,240 B
  float* srcGate2    = (float*)(ws + 36196608);               //    266,240 B -> ends 36,462,848

  hipLaunchKernelGGL(k_prep,    dim3(1024), dim3(256),  0, stream, w, bias, Wb, c, meta);
  hipLaunchKernelGGL(k_gating,  dim3(512),  dim3(256),  0, stream, x, wg, xb, routeE, routeG, meta);
  hipLaunchKernelGGL(k_scan,    dim3(1),    dim3(64),   0, stream, meta);
  hipLaunchKernelGGL(k_scatter, dim3(64),   dim3(1024), 0, stream, routeE, routeG, meta,
                     srcTok1, srcGate1, srcTok2, srcGate2);
  hipLaunchKernelGGL(k_gemm,    dim3(520),  dim3(512),  0, stream, xb, Wb,
                     meta,     meta + 16, srcTok1, srcGate1, c, out, 0);
  hipLaunchKernelGGL(k_gemm,    dim3(520),  dim3(512),  0, stream, xb, Wb,
                     meta + 8, meta + 24, srcTok2, srcGate2, c, out, 1);
}

// Round 4
// 231.374 us; speedup vs baseline: 1.1204x; 1.1204x over previous
//
#include <hip/hip_runtime.h>
#include <hip/hip_bf16.h>
#include <math.h>

#define N_TOK 65536
#define DIM   256
#define NEXP  8

using frag_ab = __attribute__((ext_vector_type(8))) short;   // 8 bf16 (4 VGPRs)
using frag_cd = __attribute__((ext_vector_type(4))) float;   // 4 fp32 acc

__device__ __forceinline__ unsigned short f2bf(float f) {
  unsigned u = __float_as_uint(f);
  u += 0x7FFFu + ((u >> 16) & 1u);   // RNE
  return (unsigned short)(u >> 16);
}

// async 16B global->LDS: lds base is wave-uniform; lane i lands at base+i*16
__device__ __forceinline__ void gl2lds16(const unsigned short* g, unsigned short* l) {
  __builtin_amdgcn_global_load_lds(
      (const __attribute__((address_space(1))) void*)g,
      (__attribute__((address_space(3))) void*)l, 16, 0, 0);
}

// meta int layout in ws: [0:8)=counts1 [8:16)=counts2 [16:24)=base1
// [24:32)=base2 [32:40)=cursor1 [40:48)=cursor2

// ---- k_prep: Wb = bf16(W) in FRAGMENT-MAJOR layout [e][k>>3][col][8]
// (so k_gemm b-frag loads are coalesced 256B segments from L2);
// c[e][o] = bias_e . W_e[o]; zero meta. --------------------------------------
__global__ __launch_bounds__(256) void k_prep(
    const float* __restrict__ w,      // expert_weight [E][OUT][D]
    const float* __restrict__ bias,   // expert_bias   [E][D]
    unsigned short* __restrict__ Wb,
    float* __restrict__ c,            // [E][OUT]
    int* __restrict__ meta) {
  int b = blockIdx.x, tid = threadIdx.x;
  if (b < 512) {
    int gid = b * 256 + tid;                  // float4 index, 131072 total
    int f0 = gid * 4;                         // flat float index
    int e = f0 >> 16;                         // 65536 floats per expert
    int fi = f0 & 65535;
    int o = fi >> 8, d = fi & 255;            // d is multiple of 4
    float4 v = ((const float4*)w)[gid];
    ushort4 h; h.x = f2bf(v.x); h.y = f2bf(v.y); h.z = f2bf(v.z); h.w = f2bf(v.w);
    // dest element = e*65536 + (d>>3)*2048 + o*8 + (d&7); as ushort4 index:
    size_t dst4 = (size_t)e * 16384 + (size_t)(d >> 3) * 512 + o * 2 + ((d & 4) >> 2);
    ((ushort4*)Wb)[dst4] = h;
    if (b == 0 && tid < 48) meta[tid] = 0;
  } else {
    int wid = ((b - 512) * 256 + tid) >> 6;   // 0..2047 : one wave per (e,o)
    int lane = tid & 63;
    int e = wid >> 8, o = wid & 255;
    const float* br = bias + e * DIM + lane * 4;
    const float* wr = w + (size_t)(e * 256 + o) * DIM + lane * 4;
    float s = br[0] * wr[0] + br[1] * wr[1] + br[2] * wr[2] + br[3] * wr[3];
    #pragma unroll
    for (int m = 1; m < 64; m <<= 1) s += __shfl_xor(s, m, 64);
    if (lane == 0) c[e * 256 + o] = s;
  }
}

// ---- k_gating: 128 tok/block, 2 threads per token (dim split), f64 ranking --
__global__ __launch_bounds__(256) void k_gating(
    const float* __restrict__ x,      // [N][D]
    const float* __restrict__ wg,     // [D][E]
    unsigned short* __restrict__ xb,  // [N][D] bf16
    int* __restrict__ routeE,         // [N] packed e1 | e2<<8
    float* __restrict__ routeG,       // [N][2]
    int* __restrict__ meta) {
  __shared__ double swg[DIM * NEXP];    // 16 KB
  __shared__ float  chunk[128 * 33];    // 16.9 KB (pad 33 -> conflict-free)
  __shared__ double sPar[128 * NEXP];   // 8 KB
  __shared__ int    hcnt[2 * NEXP];
  int tid = threadIdx.x;
  int tok0 = blockIdx.x * 128;
  int sub = tid >> 7, tk = tid & 127;

  for (int i = tid; i < DIM * NEXP; i += 256) swg[i] = (double)wg[i];
  if (tid < 2 * NEXP) hcnt[tid] = 0;

  double p[NEXP];
  #pragma unroll
  for (int e = 0; e < NEXP; e++) p[e] = 0.0;

  for (int dc = 0; dc < 8; dc++) {      // 8 chunks of 32 dims
    __syncthreads();
    #pragma unroll
    for (int i = 0; i < 4; i++) {       // stage [128 tok][32 dim], coalesced
      int f = i * 256 + tid;
      int r = f >> 3, c4 = (f & 7) * 4;
      const float4 v = *(const float4*)(x + (size_t)(tok0 + r) * DIM + dc * 32 + c4);
      ushort4 h; h.x = f2bf(v.x); h.y = f2bf(v.y); h.z = f2bf(v.z); h.w = f2bf(v.w);
      *(ushort4*)(xb + (size_t)(tok0 + r) * DIM + dc * 32 + c4) = h;
      float* dst = &chunk[r * 33 + c4];
      dst[0] = v.x; dst[1] = v.y; dst[2] = v.z; dst[3] = v.w;
    }
    __syncthreads();
    if ((dc >> 2) == sub) {             // this thread's half of the dims
      #pragma unroll 8
      for (int cc = 0; cc < 32; cc++) {
        double xv = (double)chunk[tk * 33 + cc];
        const double* wrow = &swg[(dc * 32 + cc) * NEXP];  // broadcast read
        #pragma unroll
        for (int e = 0; e < NEXP; e++) p[e] += xv * wrow[e];
      }
    }
  }

  if (sub == 1) {
    #pragma unroll
    for (int e = 0; e < NEXP; e++) sPar[tk * NEXP + e] = p[e];
  }
  __syncthreads();
  if (sub == 0) {
    #pragma unroll
    for (int e = 0; e < NEXP; e++) p[e] += sPar[tk * NEXP + e];

    // top-2 (ties -> lowest index, matches jax.lax.top_k)
    int i1 = 0; double v1 = p[0];
    #pragma unroll
    for (int e = 1; e < NEXP; e++) { if (p[e] > v1) { v1 = p[e]; i1 = e; } }
    int i2 = -1; double v2 = -1e300;
    #pragma unroll
    for (int e = 0; e < NEXP; e++) { if (e != i1 && p[e] > v2) { v2 = p[e]; i2 = e; } }
    double t = exp(v2 - v1);
    float g1 = (float)(1.0 / (1.0 + t));
    float g2 = 1.0f - g1;

    int n = tok0 + tk;
    routeE[n] = i1 | (i2 << 8);
    *(float2*)(routeG + 2 * (size_t)n) = make_float2(g1, g2);
    atomicAdd(&hcnt[i1], 1);
    atomicAdd(&hcnt[NEXP + i2], 1);
  }
  __syncthreads();
  if (tid < 2 * NEXP) atomicAdd(&meta[tid], hcnt[tid]);
}

// ---- k_scan: 128-aligned exclusive scans -> base1/2, cursor1/2 --------------
__global__ void k_scan(int* __restrict__ meta) {
  if (threadIdx.x == 0) {
    int run = 0;
    for (int e = 0; e < NEXP; e++) {
      meta[16 + e] = run; meta[32 + e] = run;          // base1, cursor1
      run += ((meta[e] + 127) >> 7) << 7;
    }
    run = 0;
    for (int e = 0; e < NEXP; e++) {
      meta[24 + e] = run; meta[40 + e] = run;          // base2, cursor2
      run += ((meta[8 + e] + 127) >> 7) << 7;
    }
  }
}

// ---- k_scatter: two expert-grouped permutations (first/second choice) -------
__global__ __launch_bounds__(1024) void k_scatter(
    const int* __restrict__ routeE, const float* __restrict__ routeG,
    int* __restrict__ meta,
    int* __restrict__ srcTok1, float* __restrict__ srcGate1,
    int* __restrict__ srcTok2, float* __restrict__ srcGate2) {
  __shared__ int cnt[2 * NEXP], bse[2 * NEXP];
  int tid = threadIdx.x;
  if (tid < 2 * NEXP) cnt[tid] = 0;
  __syncthreads();
  int n = blockIdx.x * 1024 + tid;
  int ep = routeE[n];
  int e1 = ep & 255, e2 = ep >> 8;
  float2 g = *(const float2*)(routeG + 2 * (size_t)n);
  int r1 = atomicAdd(&cnt[e1], 1);
  int r2 = atomicAdd(&cnt[NEXP + e2], 1);
  __syncthreads();
  if (tid < NEXP)            bse[tid] = atomicAdd(&meta[32 + tid], cnt[tid]);
  else if (tid < 2 * NEXP)   bse[tid] = atomicAdd(&meta[40 + (tid - NEXP)], cnt[tid]);
  __syncthreads();
  int p1 = bse[e1] + r1;
  srcTok1[p1] = n; srcGate1[p1] = g.x;
  int p2 = bse[NEXP + e2] + r2;
  srcTok2[p2] = n; srcGate2[p2] = g.y;
}

// ---- k_gemm: grouped GEMM. BM=128, BN=256 (full OUT), BK=64, 512 thr/8 waves
// A: LDS double-buffer (32 KB only), proven XOR swizzle (chunk c of row r at
// pos (c+r)&7), 2-phase prefetch identical to round-3's verified structure.
// B: read DIRECTLY from global (L2-resident, 1 MB total) in fragment-major
// layout [e][k>>3][col][8] -> each b-frag load is coalesced 256B segments.
// Small LDS (~35 KB) + <=128 VGPR -> 2 blocks/CU = 16 waves/CU (block-level
// TLP restored: the proven round-0 latency-hiding mechanism).
// mode 0: out[n] = g*(acc - c[e]); mode 1: out[n] += g*(acc - c[e])
__global__ __launch_bounds__(512, 4) void k_gemm(
    const unsigned short* __restrict__ xb,
    const unsigned short* __restrict__ Wb,   // fragment-major, see k_prep
    const int* __restrict__ counts, const int* __restrict__ base,
    const int* __restrict__ srcTok, const float* __restrict__ srcGate,
    const float* __restrict__ c,
    float* __restrict__ out, int mode) {
  __shared__ unsigned short sA[2][128 * 64];   // 32 KB (2 bufs)
  __shared__ int   sTok[128];
  __shared__ float sG[128];
  __shared__ float sCor[256];
  int tid = threadIdx.x;

  // map block -> (expert, m-tile)
  int rem = blockIdx.x, e = 0, ne = 0;
  for (e = 0; e < NEXP; e++) {
    ne = counts[e];
    int tiles = (ne + 127) >> 7;
    if (rem < tiles) break;
    rem -= tiles;
  }
  if (e == NEXP) return;
  int mt = rem;
  int slot0 = base[e] + mt * 128;

  if (tid < 128) {
    int idx = mt * 128 + tid;
    bool v = idx < ne;
    sTok[tid] = v ? srcTok[slot0 + tid] : 0;
    sG[tid]   = v ? srcGate[slot0 + tid] : 0.f;
  } else if (tid < 192) {
    ((float4*)sCor)[tid - 128] = ((const float4*)(c + e * 256))[tid - 128];
  }
  __syncthreads();

  int w = tid >> 6, lane = tid & 63;
  int lrow = lane >> 3, lchk = lane & 7;

  // A staging: wave w -> rows [w*16, w*16+16) (2 groups of 8 rows)
  const unsigned short* aSrc[2];
  int aOff[2];
  #pragma unroll
  for (int q = 0; q < 2; q++) {
    int r0 = w * 16 + q * 8;
    int r  = r0 + lrow;
    int cc = (lchk - r) & 7;                 // global chunk for this lane's pos
    aSrc[q] = xb + (size_t)sTok[r] * 256 + cc * 8;
    aOff[q] = r0 * 64;                       // wave-uniform LDS base (elements)
  }

  // A fragment read offsets: row ra, k-chunk kc=ks*4+lk -> pos (kc+ra)&7
  int wm = w & 1, wn = w >> 1;               // 2 (m) x 4 (n) waves
  int lr = lane & 15, lk = lane >> 4;
  int offA[2][4];
  #pragma unroll
  for (int ks = 0; ks < 2; ks++)
    #pragma unroll
    for (int i = 0; i < 4; i++) {
      int ra = wm * 64 + i * 16 + lr;
      offA[ks][i] = ra * 64 + ((ks * 4 + lk + ra) & 7) * 8;
    }

  // B fragment base (fragment-major global layout):
  // element(e, col, k) at e*65536 + (k>>3)*2048 + col*8 + (k&7)
  // frag(kk,ks,j): col = wn*64 + j*16 + lr, kg = kk*8 + ks*4 + lk
  const unsigned short* bBase =
      Wb + (size_t)e * 65536 + (size_t)lk * 2048 + (wn * 64 + lr) * 8;

  frag_cd acc[4][4];
  #pragma unroll
  for (int i = 0; i < 4; i++)
    #pragma unroll
    for (int j = 0; j < 4; j++)
      acc[i][j] = (frag_cd){0.f, 0.f, 0.f, 0.f};

#define STAGE(T, BUF) do {                                                  \
    _Pragma("unroll")                                                       \
    for (int q = 0; q < 2; q++) gl2lds16(aSrc[q] + (T) * 64, &sA[BUF][aOff[q]]); \
  } while (0)

#define COMPUTE(BUF, T) do {                                                \
    const unsigned short* A_ = sA[BUF];                                     \
    _Pragma("unroll")                                                       \
    for (int ks = 0; ks < 2; ks++) {                                        \
      frag_ab av[4], bv[4];                                                 \
      _Pragma("unroll")                                                     \
      for (int j = 0; j < 4; j++)                                           \
        bv[j] = *(const frag_ab*)(bBase + (T) * 16384 + ks * 8192 + j * 128); \
      _Pragma("unroll")                                                     \
      for (int i = 0; i < 4; i++) av[i] = *(const frag_ab*)(A_ + offA[ks][i]); \
      _Pragma("unroll")                                                     \
      for (int i = 0; i < 4; i++)                                           \
        _Pragma("unroll")                                                   \
        for (int j = 0; j < 4; j++)                                         \
          acc[i][j] = __builtin_amdgcn_mfma_f32_16x16x32_bf16(av[i], bv[j], acc[i][j], 0, 0, 0); \
    }                                                                       \
  } while (0)

  // K = 256, 4 tiles of BK=64. 2-phase: stage(t+1) issued before compute(t);
  // __syncthreads() = s_waitcnt vmcnt(0) lgkmcnt(0) + s_barrier (verified
  // correct in round 3; only A is staged now).
  STAGE(0, 0);
  __syncthreads();               // tile 0 resident
  STAGE(1, 1);                   // prefetch t1 (in flight during compute t0)
  COMPUTE(0, 0);
  __syncthreads();               // t1 resident; buf0 readers done
  STAGE(2, 0);
  COMPUTE(1, 1);
  __syncthreads();               // t2 resident; buf1 readers done
  STAGE(3, 1);
  COMPUTE(0, 2);
  __syncthreads();               // t3 resident; buf0 readers done
  COMPUTE(1, 3);

#undef STAGE
#undef COMPUTE

  // epilogue: C/D layout col=lane&15, row=(lane>>4)*4+reg  [m89-verified]
  #pragma unroll
  for (int i = 0; i < 4; i++) {
    #pragma unroll
    for (int rr = 0; rr < 4; rr++) {
      int m = wm * 64 + i * 16 + lk * 4 + rr;
      if (mt * 128 + m < ne) {             // pad rows: no store
        int tokn = sTok[m];
        float g = sG[m];
        float* orow = out + (size_t)tokn * 256;
        #pragma unroll
        for (int j = 0; j < 4; j++) {
          int col = wn * 64 + j * 16 + lr;
          float v = g * (acc[i][j][rr] - sCor[col]);
          if (mode) v += orow[col];
          orow[col] = v;
        }
      }
    }
  }
}

extern "C" void kernel_launch(void* const* d_in, const int* in_sizes, int n_in,
                              void* d_out, int out_size, void* d_ws, size_t ws_size,
                              hipStream_t stream) {
  const float* x    = (const float*)d_in[0];  // [N][D]
  const float* wg   = (const float*)d_in[1];  // [D][E]
  const float* bias = (const float*)d_in[2];  // [E][D]
  const float* w    = (const float*)d_in[3];  // [E][OUT][D]
  float* out = (float*)d_out;
  char* ws = (char*)d_ws;

  // total ws usage: ~36.5 MB (round-1 proved >=39.6 MB available)
  unsigned short* xb = (unsigned short*)(ws);                 // 33,554,432 B
  unsigned short* Wb = (unsigned short*)(ws + 33554432);      //  1,048,576 B
  float* c           = (float*)(ws + 34603008);               //      8,192 B
  int* meta          = (int*)(ws + 34611200);                 //        256 B
  int* routeE        = (int*)(ws + 34611456);                 //    262,144 B
  float* routeG      = (float*)(ws + 34873600);               //    524,288 B
  int* srcTok1       = (int*)(ws + 35397888);                 //    266,240 B (66560 slots)
  float* srcGate1    = (float*)(ws + 35664128);               //    266,240 B
  int* srcTok2       = (int*)(ws + 35930368);                 //    266,240 B
  float* srcGate2    = (float*)(ws + 36196608);               //    266,240 B -> ends 36,462,848

  hipLaunchKernelGGL(k_prep,    dim3(1024), dim3(256),  0, stream, w, bias, Wb, c, meta);
  hipLaunchKernelGGL(k_gating,  dim3(512),  dim3(256),  0, stream, x, wg, xb, routeE, routeG, meta);
  hipLaunchKernelGGL(k_scan,    dim3(1),    dim3(64),   0, stream, meta);
  hipLaunchKernelGGL(k_scatter, dim3(64),   dim3(1024), 0, stream, routeE, routeG, meta,
                     srcTok1, srcGate1, srcTok2, srcGate2);
  hipLaunchKernelGGL(k_gemm,    dim3(520),  dim3(512),  0, stream, xb, Wb,
                     meta,     meta + 16, srcTok1, srcGate1, c, out, 0);
  hipLaunchKernelGGL(k_gemm,    dim3(520),  dim3(512),  0, stream, xb, Wb,
                     meta + 8, meta + 24, srcTok2, srcGate2, c, out, 1);
}

// Round 5
// 197.565 us; speedup vs baseline: 1.3121x; 1.1711x over previous
//
#include <hip/hip_runtime.h>
#include <hip/hip_bf16.h>
#include <math.h>

#define N_TOK 65536
#define DIM   256
#define NEXP  8

using frag_ab = __attribute__((ext_vector_type(8))) short;   // 8 bf16 (4 VGPRs)
using frag_cd = __attribute__((ext_vector_type(4))) float;   // 4 fp32 acc

__device__ __forceinline__ unsigned short f2bf(float f) {
  unsigned u = __float_as_uint(f);
  u += 0x7FFFu + ((u >> 16) & 1u);   // RNE
  return (unsigned short)(u >> 16);
}

// async 16B global->LDS: lds base is wave-uniform; lane i lands at base+i*16
__device__ __forceinline__ void gl2lds16(const unsigned short* g, unsigned short* l) {
  __builtin_amdgcn_global_load_lds(
      (const __attribute__((address_space(1))) void*)g,
      (__attribute__((address_space(3))) void*)l, 16, 0, 0);
}

// meta int layout in ws: [0:64)=pair counts, [64:128)=pair base, [128:192)=cursor

// ---- k_prep: one wave per (e,o) row. Reads w ONCE: converts to bf16
// fragment-major Wb [e][k>>3][col][8] AND computes c[e][o]=bias_e.W_e[o].
__global__ __launch_bounds__(256) void k_prep(
    const float* __restrict__ w,      // expert_weight [E][OUT][D]
    const float* __restrict__ bias,   // expert_bias   [E][D]
    unsigned short* __restrict__ Wb,
    float* __restrict__ c,            // [E][OUT]
    int* __restrict__ meta) {
  int tid = threadIdx.x;
  int wid = (blockIdx.x * 256 + tid) >> 6;    // 0..2047 : one wave per (e,o)
  int lane = tid & 63;
  int e = wid >> 8, o = wid & 255;
  const float* wr = w + (size_t)(e * 256 + o) * DIM + lane * 4;
  float4 wv = *(const float4*)wr;             // row read once, coalesced
  const float* br = bias + e * DIM + lane * 4;
  float4 bv = *(const float4*)br;             // 8 KB total, L2-hot
  float s = wv.x * bv.x + wv.y * bv.y + wv.z * bv.z + wv.w * bv.w;
  #pragma unroll
  for (int m = 1; m < 64; m <<= 1) s += __shfl_xor(s, m, 64);
  if (lane == 0) c[e * 256 + o] = s;
  // fragment-major store: d = lane*4 -> elem e*65536 + (d>>3)*2048 + o*8 + (d&7)
  ushort4 h; h.x = f2bf(wv.x); h.y = f2bf(wv.y); h.z = f2bf(wv.z); h.w = f2bf(wv.w);
  *(ushort4*)(Wb + (size_t)e * 65536 + (size_t)(lane >> 1) * 2048 + o * 8 + (lane & 1) * 4) = h;
  if (blockIdx.x == 0 && tid < 192) meta[tid] = 0;
}

// ---- k_gating: 128 tok/block, 2 threads per token (dim split), f64 ranking --
// Now histograms the 64 PAIR-ids (a*8+b, a=min(e1,e2), b=max) into meta[0:64).
__global__ __launch_bounds__(256) void k_gating(
    const float* __restrict__ x,      // [N][D]
    const float* __restrict__ wg,     // [D][E]
    unsigned short* __restrict__ xb,  // [N][D] bf16
    int* __restrict__ routeE,         // [N] packed e1 | e2<<8
    float* __restrict__ routeG,       // [N][2]
    int* __restrict__ meta) {
  __shared__ double swg[DIM * NEXP];    // 16 KB
  __shared__ float  chunk[128 * 33];    // 16.9 KB (pad 33 -> conflict-free)
  __shared__ double sPar[128 * NEXP];   // 8 KB
  __shared__ int    hcnt[64];
  int tid = threadIdx.x;
  int tok0 = blockIdx.x * 128;
  int sub = tid >> 7, tk = tid & 127;

  for (int i = tid; i < DIM * NEXP; i += 256) swg[i] = (double)wg[i];
  if (tid < 64) hcnt[tid] = 0;

  double p[NEXP];
  #pragma unroll
  for (int e = 0; e < NEXP; e++) p[e] = 0.0;

  for (int dc = 0; dc < 8; dc++) {      // 8 chunks of 32 dims
    __syncthreads();
    #pragma unroll
    for (int i = 0; i < 4; i++) {       // stage [128 tok][32 dim], coalesced
      int f = i * 256 + tid;
      int r = f >> 3, c4 = (f & 7) * 4;
      const float4 v = *(const float4*)(x + (size_t)(tok0 + r) * DIM + dc * 32 + c4);
      ushort4 h; h.x = f2bf(v.x); h.y = f2bf(v.y); h.z = f2bf(v.z); h.w = f2bf(v.w);
      *(ushort4*)(xb + (size_t)(tok0 + r) * DIM + dc * 32 + c4) = h;
      float* dst = &chunk[r * 33 + c4];
      dst[0] = v.x; dst[1] = v.y; dst[2] = v.z; dst[3] = v.w;
    }
    __syncthreads();
    if ((dc >> 2) == sub) {             // this thread's half of the dims
      #pragma unroll 8
      for (int cc = 0; cc < 32; cc++) {
        double xv = (double)chunk[tk * 33 + cc];
        const double* wrow = &swg[(dc * 32 + cc) * NEXP];  // broadcast read
        #pragma unroll
        for (int e = 0; e < NEXP; e++) p[e] += xv * wrow[e];
      }
    }
  }

  if (sub == 1) {
    #pragma unroll
    for (int e = 0; e < NEXP; e++) sPar[tk * NEXP + e] = p[e];
  }
  __syncthreads();
  if (sub == 0) {
    #pragma unroll
    for (int e = 0; e < NEXP; e++) p[e] += sPar[tk * NEXP + e];

    // top-2 (ties -> lowest index, matches jax.lax.top_k)
    int i1 = 0; double v1 = p[0];
    #pragma unroll
    for (int e = 1; e < NEXP; e++) { if (p[e] > v1) { v1 = p[e]; i1 = e; } }
    int i2 = -1; double v2 = -1e300;
    #pragma unroll
    for (int e = 0; e < NEXP; e++) { if (e != i1 && p[e] > v2) { v2 = p[e]; i2 = e; } }
    double t = exp(v2 - v1);
    float g1 = (float)(1.0 / (1.0 + t));
    float g2 = 1.0f - g1;

    int n = tok0 + tk;
    routeE[n] = i1 | (i2 << 8);
    *(float2*)(routeG + 2 * (size_t)n) = make_float2(g1, g2);
    int a = i1 < i2 ? i1 : i2, b = i1 < i2 ? i2 : i1;
    atomicAdd(&hcnt[a * 8 + b], 1);
  }
  __syncthreads();
  if (tid < 64) atomicAdd(&meta[tid], hcnt[tid]);
}

// ---- k_scan: 128-aligned exclusive scan over 64 pair counts ----------------
__global__ void k_scan(int* __restrict__ meta) {
  if (threadIdx.x == 0) {
    int run = 0;
    for (int p = 0; p < 64; p++) {
      meta[64 + p] = run; meta[128 + p] = run;         // base, cursor
      run += ((meta[p] + 127) >> 7) << 7;
    }
  }
}

// ---- k_scatter: pair-grouped permutation; both gates per token --------------
__global__ __launch_bounds__(1024) void k_scatter(
    const int* __restrict__ routeE, const float* __restrict__ routeG,
    int* __restrict__ meta,
    int* __restrict__ srcTok, float* __restrict__ srcGA, float* __restrict__ srcGB) {
  __shared__ int cnt[64], bse[64];
  int tid = threadIdx.x;
  if (tid < 64) cnt[tid] = 0;
  __syncthreads();
  int n = blockIdx.x * 1024 + tid;
  int ep = routeE[n];
  int e1 = ep & 255, e2 = ep >> 8;
  float2 g = *(const float2*)(routeG + 2 * (size_t)n);
  int a = e1 < e2 ? e1 : e2, b = e1 < e2 ? e2 : e1;
  float ga = e1 < e2 ? g.x : g.y;      // gate of expert a (=min)
  float gb = e1 < e2 ? g.y : g.x;      // gate of expert b (=max)
  int pid = a * 8 + b;
  int r = atomicAdd(&cnt[pid], 1);
  __syncthreads();
  if (tid < 64) bse[tid] = atomicAdd(&meta[128 + tid], cnt[tid]);
  __syncthreads();
  int p = bse[pid] + r;
  srcTok[p] = n; srcGA[p] = ga; srcGB[p] = gb;
}

// ---- k_gemm_pair: pair-grouped fused GEMM. BM=128 tok, BN=256 (full OUT),
// 512 thr / 8 waves (2m x 4n). A-tile (128x256, 64 KB) staged ONCE via
// gl2lds with proven XOR swizzle (chunk c of row r at slot (c+r)&7), then
// ZERO barriers: phase A = 4 K-steps vs W_a, per-row acc *= sGA/sGB,
// phase B = 4 K-steps vs W_b. B-fragments stream from L2 (fragment-major).
// out written ONCE: v = sGB*acc - (sGA*cA[col] + sGB*cB[col]).
__global__ __launch_bounds__(512, 2) void k_gemm_pair(
    const unsigned short* __restrict__ xb,
    const unsigned short* __restrict__ Wb,   // fragment-major, see k_prep
    const int* __restrict__ meta,            // counts@0, base@64
    const int* __restrict__ srcTok,
    const float* __restrict__ srcGA, const float* __restrict__ srcGB,
    const float* __restrict__ c,
    float* __restrict__ out) {
  __shared__ unsigned short sA[4][128 * 64];   // 64 KB: all 4 K-subtiles
  __shared__ int   sTok[128];
  __shared__ float sGAs[128], sGBs[128];
  __shared__ float sCorA[256], sCorB[256];
  int tid = threadIdx.x;

  // map block -> (pair, m-tile)
  int rem = blockIdx.x, pid = 0, ne = 0;
  for (pid = 0; pid < 64; pid++) {
    ne = meta[pid];
    int tiles = (ne + 127) >> 7;
    if (rem < tiles) break;
    rem -= tiles;
  }
  if (pid == 64) return;
  int ea = pid >> 3, eb = pid & 7;
  int mt = rem;
  int slot0 = meta[64 + pid] + mt * 128;

  if (tid < 128) {
    int idx = mt * 128 + tid;
    bool v = idx < ne;
    sTok[tid]  = v ? srcTok[slot0 + tid] : 0;
    sGAs[tid]  = v ? srcGA[slot0 + tid] : 0.f;
    sGBs[tid]  = v ? srcGB[slot0 + tid] : 1.f;   // pad: ratio 0, never stored
  } else if (tid < 192) {
    ((float4*)sCorA)[tid - 128] = ((const float4*)(c + ea * 256))[tid - 128];
  } else if (tid < 256) {
    ((float4*)sCorB)[tid - 192] = ((const float4*)(c + eb * 256))[tid - 192];
  }
  __syncthreads();                       // sTok ready for staging addresses

  int w = tid >> 6, lane = tid & 63;
  int lrow = lane >> 3, lchk = lane & 7;

  // A staging: wave w -> rows [w*16, w*16+16), 2 groups of 8 rows, 4 subtiles
  #pragma unroll
  for (int q = 0; q < 2; q++) {
    int r0 = w * 16 + q * 8;
    int r  = r0 + lrow;
    int cc = (lchk - r) & 7;             // global chunk for this lane's slot
    const unsigned short* src = xb + (size_t)sTok[r] * 256 + cc * 8;
    #pragma unroll
    for (int kk = 0; kk < 4; kk++)
      gl2lds16(src + kk * 64, &sA[kk][r0 * 64]);
  }
  __syncthreads();   // full drain once; sA read-only hereafter -> NO barriers

  // A fragment read offsets: row ra, k-chunk kc=ks*4+lk -> slot (kc+ra)&7
  int wm = w & 1, wn = w >> 1;           // 2 (m) x 4 (n) waves
  int lr = lane & 15, lk = lane >> 4;
  int offA[2][4];
  #pragma unroll
  for (int ks = 0; ks < 2; ks++)
    #pragma unroll
    for (int i = 0; i < 4; i++) {
      int ra = wm * 64 + i * 16 + lr;
      offA[ks][i] = ra * 64 + ((ks * 4 + lk + ra) & 7) * 8;
    }

  // B fragment bases (fragment-major): elem(e,col,k) at e*65536+(k>>3)*2048+col*8+(k&7)
  const unsigned short* bBaseA =
      Wb + (size_t)ea * 65536 + (size_t)lk * 2048 + (wn * 64 + lr) * 8;
  const unsigned short* bBaseB =
      Wb + (size_t)eb * 65536 + (size_t)lk * 2048 + (wn * 64 + lr) * 8;

  frag_cd acc[4][4];
  #pragma unroll
  for (int i = 0; i < 4; i++)
    #pragma unroll
    for (int j = 0; j < 4; j++)
      acc[i][j] = (frag_cd){0.f, 0.f, 0.f, 0.f};

#define PHASE(BB) do {                                                      \
    _Pragma("unroll")                                                       \
    for (int kk = 0; kk < 4; kk++) {                                        \
      _Pragma("unroll")                                                     \
      for (int ks = 0; ks < 2; ks++) {                                      \
        frag_ab av[4], bv[4];                                               \
        _Pragma("unroll")                                                   \
        for (int j = 0; j < 4; j++)                                         \
          bv[j] = *(const frag_ab*)((BB) + kk * 16384 + ks * 8192 + j * 128); \
        _Pragma("unroll")                                                   \
        for (int i = 0; i < 4; i++) av[i] = *(const frag_ab*)(&sA[kk][0] + offA[ks][i]); \
        _Pragma("unroll")                                                   \
        for (int i = 0; i < 4; i++)                                         \
          _Pragma("unroll")                                                 \
          for (int j = 0; j < 4; j++)                                       \
            acc[i][j] = __builtin_amdgcn_mfma_f32_16x16x32_bf16(av[i], bv[j], acc[i][j], 0, 0, 0); \
      }                                                                     \
    }                                                                       \
  } while (0)

  PHASE(bBaseA);                         // acc = x @ Wa^T

  // per-row rescale: acc *= sGA[m]/sGB[m]  (bounded by e^(top2 logit gap))
  #pragma unroll
  for (int i = 0; i < 4; i++)
    #pragma unroll
    for (int rr = 0; rr < 4; rr++) {
      int m = wm * 64 + i * 16 + lk * 4 + rr;
      float ratio = sGAs[m] / sGBs[m];
      #pragma unroll
      for (int j = 0; j < 4; j++) acc[i][j][rr] *= ratio;
    }

  PHASE(bBaseB);                         // acc = (sGA/sGB)(x@Wa^T) + x@Wb^T

#undef PHASE

  // epilogue: C/D layout col=lane&15, row=(lane>>4)*4+reg  [m89-verified]
  // v = sGB*acc - (sGA*cA[col] + sGB*cB[col]); single write, no RMW.
  #pragma unroll
  for (int i = 0; i < 4; i++) {
    #pragma unroll
    for (int rr = 0; rr < 4; rr++) {
      int m = wm * 64 + i * 16 + lk * 4 + rr;
      if (mt * 128 + m < ne) {             // pad rows: no store
        int tokn = sTok[m];
        float sa = sGAs[m], sb = sGBs[m];
        float* orow = out + (size_t)tokn * 256;
        #pragma unroll
        for (int j = 0; j < 4; j++) {
          int col = wn * 64 + j * 16 + lr;
          orow[col] = sb * acc[i][j][rr] - (sa * sCorA[col] + sb * sCorB[col]);
        }
      }
    }
  }
}

extern "C" void kernel_launch(void* const* d_in, const int* in_sizes, int n_in,
                              void* d_out, int out_size, void* d_ws, size_t ws_size,
                              hipStream_t stream) {
  const float* x    = (const float*)d_in[0];  // [N][D]
  const float* wg   = (const float*)d_in[1];  // [D][E]
  const float* bias = (const float*)d_in[2];  // [E][D]
  const float* w    = (const float*)d_in[3];  // [E][OUT][D]
  float* out = (float*)d_out;
  char* ws = (char*)d_ws;

  // total ws usage: ~36.2 MB (proven >=39.6 MB available)
  unsigned short* xb = (unsigned short*)(ws);                 // 33,554,432 B
  unsigned short* Wb = (unsigned short*)(ws + 33554432);      //  1,048,576 B
  float* c           = (float*)(ws + 34603008);               //      8,192 B
  int* meta          = (int*)(ws + 34611200);                 //      1,024 B (192 ints used)
  int* routeE        = (int*)(ws + 34612224);                 //    262,144 B
  float* routeG      = (float*)(ws + 34874368);               //    524,288 B
  int* srcTok        = (int*)(ws + 35398656);                 //    280,064 B (70016 slots)
  float* srcGA       = (float*)(ws + 35678720);               //    280,064 B
  float* srcGB       = (float*)(ws + 35958784);               //    280,064 B -> ends 36,238,848

  hipLaunchKernelGGL(k_prep,      dim3(512),  dim3(256),  0, stream, w, bias, Wb, c, meta);
  hipLaunchKernelGGL(k_gating,    dim3(512),  dim3(256),  0, stream, x, wg, xb, routeE, routeG, meta);
  hipLaunchKernelGGL(k_scan,      dim3(1),    dim3(64),   0, stream, meta);
  hipLaunchKernelGGL(k_scatter,   dim3(64),   dim3(1024), 0, stream, routeE, routeG, meta,
                     srcTok, srcGA, srcGB);
  // max tiles = 65536/128 + 28 pads = 540; launch 544
  hipLaunchKernelGGL(k_gemm_pair, dim3(544),  dim3(512),  0, stream, xb, Wb,
                     meta, srcTok, srcGA, srcGB, c, out);
}

// Round 6
// 180.401 us; speedup vs baseline: 1.4369x; 1.0951x over previous
//
#include <hip/hip_runtime.h>
#include <hip/hip_bf16.h>
#include <math.h>

#define N_TOK 65536
#define DIM   256
#define NEXP  8

using frag_ab = __attribute__((ext_vector_type(8))) short;   // 8 bf16 (4 VGPRs)
using frag_cd = __attribute__((ext_vector_type(4))) float;   // 4 fp32 acc

__device__ __forceinline__ unsigned short f2bf(float f) {
  unsigned u = __float_as_uint(f);
  u += 0x7FFFu + ((u >> 16) & 1u);   // RNE
  return (unsigned short)(u >> 16);
}

// async 16B global->LDS: lds base is wave-uniform; lane i lands at base+i*16
__device__ __forceinline__ void gl2lds16(const unsigned short* g, unsigned short* l) {
  __builtin_amdgcn_global_load_lds(
      (const __attribute__((address_space(1))) void*)g,
      (__attribute__((address_space(3))) void*)l, 16, 0, 0);
}

// meta int layout in ws: [0:64)=pair counts, [64:128)=pair base, [128:192)=cursor

// ---- k_prep: one wave per (e,o) row. Reads w ONCE: converts to bf16
// fragment-major Wb [e][k>>3][col][8] AND computes c[e][o]=bias_e.W_e[o].
__global__ __launch_bounds__(256) void k_prep(
    const float* __restrict__ w,      // expert_weight [E][OUT][D]
    const float* __restrict__ bias,   // expert_bias   [E][D]
    unsigned short* __restrict__ Wb,
    float* __restrict__ c,            // [E][OUT]
    int* __restrict__ meta) {
  int tid = threadIdx.x;
  int wid = (blockIdx.x * 256 + tid) >> 6;    // 0..2047 : one wave per (e,o)
  int lane = tid & 63;
  int e = wid >> 8, o = wid & 255;
  const float* wr = w + (size_t)(e * 256 + o) * DIM + lane * 4;
  float4 wv = *(const float4*)wr;             // row read once, coalesced
  const float* br = bias + e * DIM + lane * 4;
  float4 bv = *(const float4*)br;             // 8 KB total, L2-hot
  float s = wv.x * bv.x + wv.y * bv.y + wv.z * bv.z + wv.w * bv.w;
  #pragma unroll
  for (int m = 1; m < 64; m <<= 1) s += __shfl_xor(s, m, 64);
  if (lane == 0) c[e * 256 + o] = s;
  // fragment-major store: d = lane*4 -> elem e*65536 + (d>>3)*2048 + o*8 + (d&7)
  ushort4 h; h.x = f2bf(wv.x); h.y = f2bf(wv.y); h.z = f2bf(wv.z); h.w = f2bf(wv.w);
  *(ushort4*)(Wb + (size_t)e * 65536 + (size_t)(lane >> 1) * 2048 + o * 8 + (lane & 1) * 4) = h;
  if (blockIdx.x == 0 && tid < 192) meta[tid] = 0;
}

// ---- k_gating v2: 64 tok/block (1024 blocks -> 4 blocks/CU), 256 threads =
// 4 threads/token (dims cc === sub mod 4). Register double-buffer: chunk dc+1
// loaded to regs before computing dc (overlap). Reduce: 4-lane f64 butterfly
// (no sPar LDS, no extra barrier). f64 math identical; only the summation
// partition changes (1e-16 perturbation vs ~1e-5 logit gaps -> ranking-safe).
__global__ __launch_bounds__(256) void k_gating(
    const float* __restrict__ x,      // [N][D]
    const float* __restrict__ wg,     // [D][E]
    unsigned short* __restrict__ xb,  // [N][D] bf16
    int* __restrict__ routeE,         // [N] packed e1 | e2<<8
    float* __restrict__ routeG,       // [N][2]
    int* __restrict__ meta) {
  __shared__ double swg[DIM * NEXP];    // 16 KB
  __shared__ float  chunk[64 * 35];     // 8.96 KB (pad 35: bank=3*tk+cc, <=3-way)
  __shared__ int    hcnt[64];
  int tid = threadIdx.x;
  int tok0 = blockIdx.x * 64;
  int tk = tid >> 2, sub = tid & 3;     // token-local id, dim-quarter

  for (int i = tid; i < DIM * NEXP; i += 256) swg[i] = (double)wg[i];
  if (tid < 64) hcnt[tid] = 0;

  double p[NEXP];
  #pragma unroll
  for (int e = 0; e < NEXP; e++) p[e] = 0.0;

  // staging map: f in [0,512) covers [64 tok][32 dim] as float4s
  int f0 = tid, f1 = 256 + tid;
  int r0 = f0 >> 3, c40 = (f0 & 7) * 4;
  int r1 = f1 >> 3, c41 = (f1 & 7) * 4;
  const float* xs0 = x + (size_t)(tok0 + r0) * DIM + c40;
  const float* xs1 = x + (size_t)(tok0 + r1) * DIM + c41;
  unsigned short* xd0 = xb + (size_t)(tok0 + r0) * DIM + c40;
  unsigned short* xd1 = xb + (size_t)(tok0 + r1) * DIM + c41;

  float4 v0 = *(const float4*)(xs0);    // chunk 0 pre-loaded
  float4 v1 = *(const float4*)(xs1);

  for (int dc = 0; dc < 8; dc++) {      // 8 chunks of 32 dims
    __syncthreads();                    // prev compute done -> chunk reusable
    // store staged regs: LDS chunk + bf16 global
    {
      ushort4 h0; h0.x = f2bf(v0.x); h0.y = f2bf(v0.y); h0.z = f2bf(v0.z); h0.w = f2bf(v0.w);
      ushort4 h1; h1.x = f2bf(v1.x); h1.y = f2bf(v1.y); h1.z = f2bf(v1.z); h1.w = f2bf(v1.w);
      *(ushort4*)(xd0 + dc * 32) = h0;
      *(ushort4*)(xd1 + dc * 32) = h1;
      float* d0 = &chunk[r0 * 35 + c40];
      d0[0] = v0.x; d0[1] = v0.y; d0[2] = v0.z; d0[3] = v0.w;
      float* d1 = &chunk[r1 * 35 + c41];
      d1[0] = v1.x; d1[1] = v1.y; d1[2] = v1.z; d1[3] = v1.w;
    }
    // issue next chunk's loads BEFORE compute (overlap with this compute)
    float4 n0 = make_float4(0.f, 0.f, 0.f, 0.f);
    float4 n1 = make_float4(0.f, 0.f, 0.f, 0.f);
    if (dc < 7) {
      n0 = *(const float4*)(xs0 + (dc + 1) * 32);
      n1 = *(const float4*)(xs1 + (dc + 1) * 32);
    }
    __syncthreads();                    // chunk visible
    #pragma unroll
    for (int c8 = 0; c8 < 8; c8++) {    // this thread's 8 dims of the chunk
      int cc = c8 * 4 + sub;
      double xv = (double)chunk[tk * 35 + cc];
      const double* wrow = &swg[(dc * 32 + cc) * NEXP];  // 4 addrs, broadcast
      #pragma unroll
      for (int e = 0; e < NEXP; e++) p[e] += xv * wrow[e];
    }
    v0 = n0; v1 = n1;
  }

  // 4-lane butterfly reduce over the dim quarters (deterministic order)
  #pragma unroll
  for (int e = 0; e < NEXP; e++) {
    p[e] += __shfl_xor(p[e], 1, 64);
    p[e] += __shfl_xor(p[e], 2, 64);
  }

  if (sub == 0) {
    // top-2 (ties -> lowest index, matches jax.lax.top_k)
    int i1 = 0; double v1d = p[0];
    #pragma unroll
    for (int e = 1; e < NEXP; e++) { if (p[e] > v1d) { v1d = p[e]; i1 = e; } }
    int i2 = -1; double v2d = -1e300;
    #pragma unroll
    for (int e = 0; e < NEXP; e++) { if (e != i1 && p[e] > v2d) { v2d = p[e]; i2 = e; } }
    double t = exp(v2d - v1d);
    float g1 = (float)(1.0 / (1.0 + t));
    float g2 = 1.0f - g1;

    int n = tok0 + tk;
    routeE[n] = i1 | (i2 << 8);
    *(float2*)(routeG + 2 * (size_t)n) = make_float2(g1, g2);
    int a = i1 < i2 ? i1 : i2, b = i1 < i2 ? i2 : i1;
    atomicAdd(&hcnt[a * 8 + b], 1);
  }
  __syncthreads();
  if (tid < 64) atomicAdd(&meta[tid], hcnt[tid]);
}

// ---- k_scan: 128-aligned exclusive scan over 64 pair counts ----------------
__global__ void k_scan(int* __restrict__ meta) {
  if (threadIdx.x == 0) {
    int run = 0;
    for (int p = 0; p < 64; p++) {
      meta[64 + p] = run; meta[128 + p] = run;         // base, cursor
      run += ((meta[p] + 127) >> 7) << 7;
    }
  }
}

// ---- k_scatter: pair-grouped permutation; both gates per token --------------
__global__ __launch_bounds__(1024) void k_scatter(
    const int* __restrict__ routeE, const float* __restrict__ routeG,
    int* __restrict__ meta,
    int* __restrict__ srcTok, float* __restrict__ srcGA, float* __restrict__ srcGB) {
  __shared__ int cnt[64], bse[64];
  int tid = threadIdx.x;
  if (tid < 64) cnt[tid] = 0;
  __syncthreads();
  int n = blockIdx.x * 1024 + tid;
  int ep = routeE[n];
  int e1 = ep & 255, e2 = ep >> 8;
  float2 g = *(const float2*)(routeG + 2 * (size_t)n);
  int a = e1 < e2 ? e1 : e2, b = e1 < e2 ? e2 : e1;
  float ga = e1 < e2 ? g.x : g.y;      // gate of expert a (=min)
  float gb = e1 < e2 ? g.y : g.x;      // gate of expert b (=max)
  int pid = a * 8 + b;
  int r = atomicAdd(&cnt[pid], 1);
  __syncthreads();
  if (tid < 64) bse[tid] = atomicAdd(&meta[128 + tid], cnt[tid]);
  __syncthreads();
  int p = bse[pid] + r;
  srcTok[p] = n; srcGA[p] = ga; srcGB[p] = gb;
}

// ---- k_gemm_pair: pair-grouped fused GEMM. BM=128 tok, BN=256 (full OUT),
// 512 thr / 8 waves (2m x 4n). A-tile (128x256, 64 KB) staged ONCE via
// gl2lds with proven XOR swizzle (chunk c of row r at slot (c+r)&7), then
// ZERO barriers: phase A = 4 K-steps vs W_a, per-row acc *= sGA/sGB,
// phase B = 4 K-steps vs W_b. B-fragments stream from L2 (fragment-major).
// out written ONCE: v = sGB*acc - (sGA*cA[col] + sGB*cB[col]).
__global__ __launch_bounds__(512, 2) void k_gemm_pair(
    const unsigned short* __restrict__ xb,
    const unsigned short* __restrict__ Wb,   // fragment-major, see k_prep
    const int* __restrict__ meta,            // counts@0, base@64
    const int* __restrict__ srcTok,
    const float* __restrict__ srcGA, const float* __restrict__ srcGB,
    const float* __restrict__ c,
    float* __restrict__ out) {
  __shared__ unsigned short sA[4][128 * 64];   // 64 KB: all 4 K-subtiles
  __shared__ int   sTok[128];
  __shared__ float sGAs[128], sGBs[128];
  __shared__ float sCorA[256], sCorB[256];
  int tid = threadIdx.x;

  // map block -> (pair, m-tile)
  int rem = blockIdx.x, pid = 0, ne = 0;
  for (pid = 0; pid < 64; pid++) {
    ne = meta[pid];
    int tiles = (ne + 127) >> 7;
    if (rem < tiles) break;
    rem -= tiles;
  }
  if (pid == 64) return;
  int ea = pid >> 3, eb = pid & 7;
  int mt = rem;
  int slot0 = meta[64 + pid] + mt * 128;

  if (tid < 128) {
    int idx = mt * 128 + tid;
    bool v = idx < ne;
    sTok[tid]  = v ? srcTok[slot0 + tid] : 0;
    sGAs[tid]  = v ? srcGA[slot0 + tid] : 0.f;
    sGBs[tid]  = v ? srcGB[slot0 + tid] : 1.f;   // pad: ratio 0, never stored
  } else if (tid < 192) {
    ((float4*)sCorA)[tid - 128] = ((const float4*)(c + ea * 256))[tid - 128];
  } else if (tid < 256) {
    ((float4*)sCorB)[tid - 192] = ((const float4*)(c + eb * 256))[tid - 192];
  }
  __syncthreads();                       // sTok ready for staging addresses

  int w = tid >> 6, lane = tid & 63;
  int lrow = lane >> 3, lchk = lane & 7;

  // A staging: wave w -> rows [w*16, w*16+16), 2 groups of 8 rows, 4 subtiles
  #pragma unroll
  for (int q = 0; q < 2; q++) {
    int r0 = w * 16 + q * 8;
    int r  = r0 + lrow;
    int cc = (lchk - r) & 7;             // global chunk for this lane's slot
    const unsigned short* src = xb + (size_t)sTok[r] * 256 + cc * 8;
    #pragma unroll
    for (int kk = 0; kk < 4; kk++)
      gl2lds16(src + kk * 64, &sA[kk][r0 * 64]);
  }
  __syncthreads();   // full drain once; sA read-only hereafter -> NO barriers

  // A fragment read offsets: row ra, k-chunk kc=ks*4+lk -> slot (kc+ra)&7
  int wm = w & 1, wn = w >> 1;           // 2 (m) x 4 (n) waves
  int lr = lane & 15, lk = lane >> 4;
  int offA[2][4];
  #pragma unroll
  for (int ks = 0; ks < 2; ks++)
    #pragma unroll
    for (int i = 0; i < 4; i++) {
      int ra = wm * 64 + i * 16 + lr;
      offA[ks][i] = ra * 64 + ((ks * 4 + lk + ra) & 7) * 8;
    }

  // B fragment bases (fragment-major): elem(e,col,k) at e*65536+(k>>3)*2048+col*8+(k&7)
  const unsigned short* bBaseA =
      Wb + (size_t)ea * 65536 + (size_t)lk * 2048 + (wn * 64 + lr) * 8;
  const unsigned short* bBaseB =
      Wb + (size_t)eb * 65536 + (size_t)lk * 2048 + (wn * 64 + lr) * 8;

  frag_cd acc[4][4];
  #pragma unroll
  for (int i = 0; i < 4; i++)
    #pragma unroll
    for (int j = 0; j < 4; j++)
      acc[i][j] = (frag_cd){0.f, 0.f, 0.f, 0.f};

#define PHASE(BB) do {                                                      \
    _Pragma("unroll")                                                       \
    for (int kk = 0; kk < 4; kk++) {                                        \
      _Pragma("unroll")                                                     \
      for (int ks = 0; ks < 2; ks++) {                                      \
        frag_ab av[4], bv[4];                                               \
        _Pragma("unroll")                                                   \
        for (int j = 0; j < 4; j++)                                         \
          bv[j] = *(const frag_ab*)((BB) + kk * 16384 + ks * 8192 + j * 128); \
        _Pragma("unroll")                                                   \
        for (int i = 0; i < 4; i++) av[i] = *(const frag_ab*)(&sA[kk][0] + offA[ks][i]); \
        _Pragma("unroll")                                                   \
        for (int i = 0; i < 4; i++)                                         \
          _Pragma("unroll")                                                 \
          for (int j = 0; j < 4; j++)                                       \
            acc[i][j] = __builtin_amdgcn_mfma_f32_16x16x32_bf16(av[i], bv[j], acc[i][j], 0, 0, 0); \
      }                                                                     \
    }                                                                       \
  } while (0)

  PHASE(bBaseA);                         // acc = x @ Wa^T

  // per-row rescale: acc *= sGA[m]/sGB[m]  (bounded by e^(top2 logit gap))
  #pragma unroll
  for (int i = 0; i < 4; i++)
    #pragma unroll
    for (int rr = 0; rr < 4; rr++) {
      int m = wm * 64 + i * 16 + lk * 4 + rr;
      float ratio = sGAs[m] / sGBs[m];
      #pragma unroll
      for (int j = 0; j < 4; j++) acc[i][j][rr] *= ratio;
    }

  PHASE(bBaseB);                         // acc = (sGA/sGB)(x@Wa^T) + x@Wb^T

#undef PHASE

  // epilogue: C/D layout col=lane&15, row=(lane>>4)*4+reg  [m89-verified]
  // v = sGB*acc - (sGA*cA[col] + sGB*cB[col]); single write, no RMW.
  #pragma unroll
  for (int i = 0; i < 4; i++) {
    #pragma unroll
    for (int rr = 0; rr < 4; rr++) {
      int m = wm * 64 + i * 16 + lk * 4 + rr;
      if (mt * 128 + m < ne) {             // pad rows: no store
        int tokn = sTok[m];
        float sa = sGAs[m], sb = sGBs[m];
        float* orow = out + (size_t)tokn * 256;
        #pragma unroll
        for (int j = 0; j < 4; j++) {
          int col = wn * 64 + j * 16 + lr;
          orow[col] = sb * acc[i][j][rr] - (sa * sCorA[col] + sb * sCorB[col]);
        }
      }
    }
  }
}

extern "C" void kernel_launch(void* const* d_in, const int* in_sizes, int n_in,
                              void* d_out, int out_size, void* d_ws, size_t ws_size,
                              hipStream_t stream) {
  const float* x    = (const float*)d_in[0];  // [N][D]
  const float* wg   = (const float*)d_in[1];  // [D][E]
  const float* bias = (const float*)d_in[2];  // [E][D]
  const float* w    = (const float*)d_in[3];  // [E][OUT][D]
  float* out = (float*)d_out;
  char* ws = (char*)d_ws;

  // total ws usage: ~36.2 MB (proven >=39.6 MB available)
  unsigned short* xb = (unsigned short*)(ws);                 // 33,554,432 B
  unsigned short* Wb = (unsigned short*)(ws + 33554432);      //  1,048,576 B
  float* c           = (float*)(ws + 34603008);               //      8,192 B
  int* meta          = (int*)(ws + 34611200);                 //      1,024 B (192 ints used)
  int* routeE        = (int*)(ws + 34612224);                 //    262,144 B
  float* routeG      = (float*)(ws + 34874368);               //    524,288 B
  int* srcTok        = (int*)(ws + 35398656);                 //    280,064 B (70016 slots)
  float* srcGA       = (float*)(ws + 35678720);               //    280,064 B
  float* srcGB       = (float*)(ws + 35958784);               //    280,064 B -> ends 36,238,848

  hipLaunchKernelGGL(k_prep,      dim3(512),  dim3(256),  0, stream, w, bias, Wb, c, meta);
  hipLaunchKernelGGL(k_gating,    dim3(1024), dim3(256),  0, stream, x, wg, xb, routeE, routeG, meta);
  hipLaunchKernelGGL(k_scan,      dim3(1),    dim3(64),   0, stream, meta);
  hipLaunchKernelGGL(k_scatter,   dim3(64),   dim3(1024), 0, stream, routeE, routeG, meta,
                     srcTok, srcGA, srcGB);
  // max tiles = 65536/128 + 28 pads = 540; launch 544
  hipLaunchKernelGGL(k_gemm_pair, dim3(544),  dim3(512),  0, stream, xb, Wb,
                     meta, srcTok, srcGA, srcGB, c, out);
}